// Round 1
// baseline (129.452 us; speedup 1.0000x reference)
//
#include <hip/hip_runtime.h>
#include <math.h>

#define TPB 256

__global__ __launch_bounds__(TPB) void jls_kernel(
    const float* __restrict__ x,
    const int* __restrict__ prefix,
    float* __restrict__ out)
{
    const int seg   = blockIdx.x;
    const int start = (seg == 0) ? 0 : prefix[seg - 1];
    const int end   = prefix[seg];
    if (end <= start) return;           // empty segment (uniform across block)

    const int tid = threadIdx.x;

    // alignment split: [start,a0) scalar head, [a0,a1) float4 body, [a1,end) scalar tail
    int a0 = (start + 3) & ~3;  if (a0 > end) a0 = end;
    int a1 = end & ~3;          if (a1 < a0) a1 = a0;
    const float4* __restrict__ x4 = (const float4*)x;
    const int v0 = a0 >> 2, v1 = a1 >> 2;

    __shared__ float sbuf[4];   // 4 waves per block

    // ---------------- pass 1: segment max ----------------
    float m = -INFINITY;
    for (int i = start + tid; i < a0; i += TPB) m = fmaxf(m, x[i]);
    for (int i = v0 + tid; i < v1; i += TPB) {
        float4 v = x4[i];
        m = fmaxf(m, fmaxf(fmaxf(v.x, v.y), fmaxf(v.z, v.w)));
    }
    for (int i = a1 + tid; i < end; i += TPB) m = fmaxf(m, x[i]);

    #pragma unroll
    for (int off = 32; off > 0; off >>= 1)
        m = fmaxf(m, __shfl_xor(m, off, 64));
    if ((tid & 63) == 0) sbuf[tid >> 6] = m;
    __syncthreads();
    m = fmaxf(fmaxf(sbuf[0], sbuf[1]), fmaxf(sbuf[2], sbuf[3]));
    __syncthreads();    // protect sbuf for reuse below

    // ---------------- pass 2: sum of exp(x - m) ----------------
    float l = 0.0f;
    for (int i = start + tid; i < a0; i += TPB) l += __expf(x[i] - m);
    for (int i = v0 + tid; i < v1; i += TPB) {
        float4 v = x4[i];
        l += __expf(v.x - m) + __expf(v.y - m) + __expf(v.z - m) + __expf(v.w - m);
    }
    for (int i = a1 + tid; i < end; i += TPB) l += __expf(x[i] - m);

    #pragma unroll
    for (int off = 32; off > 0; off >>= 1)
        l += __shfl_xor(l, off, 64);
    if ((tid & 63) == 0) sbuf[tid >> 6] = l;
    __syncthreads();
    l = sbuf[0] + sbuf[1] + sbuf[2] + sbuf[3];

    const float c = m + __logf(l);

    // ---------------- pass 3: write out = x - c ----------------
    float4* __restrict__ o4 = (float4*)out;
    for (int i = start + tid; i < a0; i += TPB) out[i] = x[i] - c;
    for (int i = v0 + tid; i < v1; i += TPB) {
        float4 v = x4[i];
        float4 r;
        r.x = v.x - c; r.y = v.y - c; r.z = v.z - c; r.w = v.w - c;
        o4[i] = r;
    }
    for (int i = a1 + tid; i < end; i += TPB) out[i] = x[i] - c;
}

extern "C" void kernel_launch(void* const* d_in, const int* in_sizes, int n_in,
                              void* d_out, int out_size, void* d_ws, size_t ws_size,
                              hipStream_t stream) {
    const float* logits = (const float*)d_in[0];
    const int*   prefix = (const int*)d_in[1];
    float*       out    = (float*)d_out;
    const int num_segs  = in_sizes[1];

    jls_kernel<<<num_segs, TPB, 0, stream>>>(logits, prefix, out);
}